// Round 1
// baseline (655.575 us; speedup 1.0000x reference)
//
#include <hip/hip_runtime.h>
#include <math.h>

#define C_DIM 512
#define K_DIM 64
#define N_PIX 784
#define B_DIM 128
#define M_ROWS (B_DIM * N_PIX)   // 100352
#define MT 128                    // rows per cost tile
#define NCH 16                    // 512 / 32 chunks
#define NTILES (M_ROWS / MT)      // 784 cost tiles
#define NPOOL (B_DIM * 4)         // 512 pool quarters
#define GRID_FUSED 768            // 3 blocks/CU at <=170 VGPR; ticket scheme is
                                  // deadlock-free at any residency (see phase A note)

// exp(20*d - 20) = exp2(KA*d + KB)
#define KA 28.853900817779268f
#define KB (-28.853900817779268f)

typedef __attribute__((ext_vector_type(8))) short short8;            // MFMA A/B frag (8 bf16)
typedef __attribute__((ext_vector_type(4))) float f32x4;             // MFMA C/D frag
typedef __attribute__((ext_vector_type(8))) unsigned short ushort8;  // 16B

static __device__ __forceinline__ unsigned short f2bf(float f) {
    unsigned u = __builtin_bit_cast(unsigned, f);
    u += 0x7fff + ((u >> 16) & 1);  // RNE
    return (unsigned short)(u >> 16);
}
static __device__ __forceinline__ float bf2f(unsigned short h) {
    unsigned u = ((unsigned)h) << 16;
    return __builtin_bit_cast(float, u);
}
static __device__ __forceinline__ unsigned pk_bf16(float a, float b) {
    return (unsigned)f2bf(a) | ((unsigned)f2bf(b) << 16);
}

// ---------------- Kernel A: normalize anchors -> bf16 hi/lo in MFMA-frag order --------------
// Also zeroes the fused kernel's tickets/done counters (ctr[0..259]) each launch.
// Frag for (chunk ch, col-tile ct, lane L) at index ((ch*4+ct)*64 + L), holding
// B[r = ct*16 + (L&15)][k = ch*32 + (L>>4)*8 .. +7]. (verified R5 of prior session)
__global__ __launch_bounds__(64) void anchors_norm_kernel(const float* __restrict__ a,
                                                          ushort8* __restrict__ an_h,
                                                          ushort8* __restrict__ an_l,
                                                          int* __restrict__ ctr) {
    const int k = blockIdx.x;
    const int l = threadIdx.x;  // 0..63
    if (k == 0) {
#pragma unroll
        for (int i = l; i < 260; i += 64) ctr[i] = 0;
    }
    const float4* ap = (const float4*)(a + (size_t)k * C_DIM);
    float4 v0 = ap[2 * l];       // cols 8l..8l+3
    float4 v1 = ap[2 * l + 1];   // cols 8l+4..8l+7
    float ss = v0.x * v0.x + v0.y * v0.y + v0.z * v0.z + v0.w * v0.w +
               v1.x * v1.x + v1.y * v1.y + v1.z * v1.z + v1.w * v1.w;
#pragma unroll
    for (int m = 1; m < 64; m <<= 1) ss += __shfl_xor(ss, m);
    const float rn = 1.0f / (sqrtf(ss) + 1e-12f);
    const float vv[8] = {v0.x * rn, v0.y * rn, v0.z * rn, v0.w * rn,
                         v1.x * rn, v1.y * rn, v1.z * rn, v1.w * rn};
    ushort8 H, L;
#pragma unroll
    for (int i = 0; i < 8; ++i) {
        const unsigned short h = f2bf(vv[i]);
        H[i] = h;
        L[i] = f2bf(vv[i] - bf2f(h));
    }
    const int idx = (((l >> 2) * 4 + (k >> 4)) * 64) + ((k & 15) | ((l & 3) << 4));
    an_h[idx] = H;
    an_l[idx] = L;
}

// ---------------- Fused kernel: cost tiles -> per-batch sinkhorn+pool, overlapped ----------
// Phase A: blocks claim cost tiles (atomic ticket) until all NTILES are claimed.
//   A block only enters phase B after observing ticketA >= NTILES, i.e. every tile
//   is claimed by a RUNNING block -> all done-counters will be released without
//   needing any not-yet-resident block => no deadlock at any occupancy.
// Phase B: blocks claim pool quarters (batch-major), spin (tid0) on the batch's
//   7-tile done counter, run the scalar sinkhorn redundantly, pool their 196 rows,
//   and the 4th finisher of a batch reduces the 8 partials -> out. x re-read is
//   L3-hot (205 MB < 256 MB L3, touched microseconds earlier by phase A).
__global__ __launch_bounds__(256) void fused_kernel(const float* __restrict__ x,
                                                    const ushort8* __restrict__ an_h,
                                                    const ushort8* __restrict__ an_l,
                                                    float* __restrict__ Tg,
                                                    float* __restrict__ part,
                                                    float* __restrict__ out,
                                                    int* __restrict__ ctr) {
    __shared__ float nrm[MT];
    __shared__ float cf[196];
    __shared__ float wsum[4];
    __shared__ float wsh;
    __shared__ int s_work;
    __shared__ int s_red;

    const int tid = threadIdx.x;
    const int w = tid >> 6;   // wave 0..3
    const int l = tid & 63;   // lane
    const int fr = l & 15;
    const int ko = (l >> 4) * 8;  // k offset within chunk (floats)

    int* doneT = ctr + 2;          // [B_DIM] cost tiles completed per batch (need 7)
    int* doneP = ctr + 2 + B_DIM;  // [B_DIM] pool quarters completed per batch

    const ushort8* bhp = an_h + l;
    const ushort8* blp = an_l + l;

    // ================= phase A: cost tiles =================
    for (;;) {
        __syncthreads();  // guard s_work + nrm reuse
        if (tid == 0)
            s_work = __hip_atomic_fetch_add(&ctr[0], 1, __ATOMIC_RELAXED, __HIP_MEMORY_SCOPE_AGENT);
        __syncthreads();
        const int tile = s_work;
        if (tile >= NTILES) break;
        const int m0 = tile * MT;

        const float* xr0 = x + (size_t)(m0 + w * 32 + fr) * C_DIM + ko;
        const float* xr1 = xr0 + 16 * C_DIM;

        f32x4 acc[2][4];
#pragma unroll
        for (int rt = 0; rt < 2; ++rt)
#pragma unroll
            for (int ct = 0; ct < 4; ++ct) acc[rt][ct] = (f32x4){0.f, 0.f, 0.f, 0.f};
        float ss0 = 0.f, ss1 = 0.f;

        // prefetch chunk 0
        float4 p0a = *(const float4*)(xr0);
        float4 p0b = *(const float4*)(xr0 + 4);
        float4 p1a = *(const float4*)(xr1);
        float4 p1b = *(const float4*)(xr1 + 4);
        ushort8 bh[4], bl[4];
#pragma unroll
        for (int ct = 0; ct < 4; ++ct) { bh[ct] = bhp[ct * 64]; bl[ct] = blp[ct * 64]; }

#pragma unroll 1
        for (int ch = 0; ch < NCH; ++ch) {
            ushort8 A0, A1;
            *((unsigned*)&A0 + 0) = pk_bf16(p0a.x, p0a.y);
            *((unsigned*)&A0 + 1) = pk_bf16(p0a.z, p0a.w);
            *((unsigned*)&A0 + 2) = pk_bf16(p0b.x, p0b.y);
            *((unsigned*)&A0 + 3) = pk_bf16(p0b.z, p0b.w);
            *((unsigned*)&A1 + 0) = pk_bf16(p1a.x, p1a.y);
            *((unsigned*)&A1 + 1) = pk_bf16(p1a.z, p1a.w);
            *((unsigned*)&A1 + 2) = pk_bf16(p1b.x, p1b.y);
            *((unsigned*)&A1 + 3) = pk_bf16(p1b.z, p1b.w);
            ss0 += p0a.x * p0a.x + p0a.y * p0a.y + p0a.z * p0a.z + p0a.w * p0a.w +
                   p0b.x * p0b.x + p0b.y * p0b.y + p0b.z * p0b.z + p0b.w * p0b.w;
            ss1 += p1a.x * p1a.x + p1a.y * p1a.y + p1a.z * p1a.z + p1a.w * p1a.w +
                   p1b.x * p1b.x + p1b.y * p1b.y + p1b.z * p1b.z + p1b.w * p1b.w;
            const short8 a0 = __builtin_bit_cast(short8, A0);
            const short8 a1 = __builtin_bit_cast(short8, A1);
            ushort8 cbh[4], cbl[4];
#pragma unroll
            for (int ct = 0; ct < 4; ++ct) { cbh[ct] = bh[ct]; cbl[ct] = bl[ct]; }

            // prefetch next chunk (overlaps MFMAs)
            if (ch + 1 < NCH) {
                const int c0 = (ch + 1) * 32;
                p0a = *(const float4*)(xr0 + c0);
                p0b = *(const float4*)(xr0 + c0 + 4);
                p1a = *(const float4*)(xr1 + c0);
                p1b = *(const float4*)(xr1 + c0 + 4);
                const int bb = (ch + 1) * 4 * 64;
#pragma unroll
                for (int ct = 0; ct < 4; ++ct) {
                    bh[ct] = bhp[bb + ct * 64];
                    bl[ct] = blp[bb + ct * 64];
                }
            }

#pragma unroll
            for (int ct = 0; ct < 4; ++ct) {
                const short8 h = __builtin_bit_cast(short8, cbh[ct]);
                const short8 lo = __builtin_bit_cast(short8, cbl[ct]);
                acc[0][ct] = __builtin_amdgcn_mfma_f32_16x16x32_bf16(a0, h, acc[0][ct], 0, 0, 0);
                acc[0][ct] = __builtin_amdgcn_mfma_f32_16x16x32_bf16(a0, lo, acc[0][ct], 0, 0, 0);
                acc[1][ct] = __builtin_amdgcn_mfma_f32_16x16x32_bf16(a1, h, acc[1][ct], 0, 0, 0);
                acc[1][ct] = __builtin_amdgcn_mfma_f32_16x16x32_bf16(a1, lo, acc[1][ct], 0, 0, 0);
            }
        }

        // full-row sumsq: lanes {l, l+16, l+32, l+48} hold complementary k-slices
        ss0 += __shfl_xor(ss0, 16); ss0 += __shfl_xor(ss0, 32);
        ss1 += __shfl_xor(ss1, 16); ss1 += __shfl_xor(ss1, 32);
        if (l < 16) {
            nrm[w * 32 + fr] = 1.0f / (sqrtf(ss0) + 1e-12f);
            nrm[w * 32 + 16 + fr] = 1.0f / (sqrtf(ss1) + 1e-12f);
        }
        __syncthreads();

        // epilogue: C/D layout col=l&15, row=(l>>4)*4+i ; T[m] = sum_k exp(20*cos - 20)
#pragma unroll
        for (int rt = 0; rt < 2; ++rt) {
#pragma unroll
            for (int i = 0; i < 4; ++i) {
                const int m = w * 32 + rt * 16 + ((l >> 4) << 2) + i;
                const float rn = nrm[m];
                float s = exp2f(KA * (acc[rt][0][i] * rn) + KB) +
                          exp2f(KA * (acc[rt][1][i] * rn) + KB) +
                          exp2f(KA * (acc[rt][2][i] * rn) + KB) +
                          exp2f(KA * (acc[rt][3][i] * rn) + KB);
                s += __shfl_xor(s, 1); s += __shfl_xor(s, 2);
                s += __shfl_xor(s, 4); s += __shfl_xor(s, 8);
                if ((l & 15) == 0) Tg[m0 + m] = s;
            }
        }

        // release this tile to its batch(es): 784 = 6.125 tiles, each batch spans
        // exactly 7 tiles (784 + max offset 112 = 896 = 7*128)
        __threadfence();
        __syncthreads();
        if (tid == 0) {
            const int b0 = m0 / N_PIX;
            const int b1 = (m0 + MT - 1) / N_PIX;
            __hip_atomic_fetch_add(&doneT[b0], 1, __ATOMIC_RELEASE, __HIP_MEMORY_SCOPE_AGENT);
            if (b1 != b0)
                __hip_atomic_fetch_add(&doneT[b1], 1, __ATOMIC_RELEASE, __HIP_MEMORY_SCOPE_AGENT);
        }
    }

    // ================= phase B: sinkhorn + pool quarters =================
    for (;;) {
        __syncthreads();  // guard s_work/cf/wsum reuse
        if (tid == 0)
            s_work = __hip_atomic_fetch_add(&ctr[1], 1, __ATOMIC_RELAXED, __HIP_MEMORY_SCOPE_AGENT);
        __syncthreads();
        const int j = s_work;
        if (j >= NPOOL) break;
        const int b = j >> 2;
        const int q = j & 3;

        if (tid == 0) {
            while (__hip_atomic_load(&doneT[b], __ATOMIC_RELAXED, __HIP_MEMORY_SCOPE_AGENT) < 7)
                __builtin_amdgcn_s_sleep(2);
        }
        __syncthreads();
        __threadfence();  // acquire: make released Tg tiles visible to plain loads

        float r[4];
#pragma unroll
        for (int qq = 0; qq < 4; ++qq) {
            const int n = tid + qq * 256;
            r[qq] = (n < N_PIX) ? Tg[b * N_PIX + n] : 0.f;
        }
        float wv = 1.0f;
        for (int it = 0; it < 10; ++it) {
            float p = 0.f;
#pragma unroll
            for (int qq = 0; qq < 4; ++qq) {
                const float wr = wv * r[qq];
                p += wr / (1.0f + wr);
            }
#pragma unroll
            for (int m = 1; m < 64; m <<= 1) p += __shfl_xor(p, m);
            if ((tid & 63) == 0) wsum[tid >> 6] = p;
            __syncthreads();
            if (tid == 0) {
                const float s = wsum[0] + wsum[1] + wsum[2] + wsum[3];
                wsh = wv * 392.0f / s;  // mu*N = 0.5*784
            }
            __syncthreads();
            wv = wsh;
        }
        if (tid < 196) {
            const float wr = wv * Tg[b * N_PIX + q * 196 + tid];
            cf[tid] = (2.0f / 784.0f) * wr / (1.0f + wr);
        }
        __syncthreads();

        const int half = tid >> 7;       // 0/1 (wave-uniform)
        const int c4 = (tid & 127) * 4;  // channel float4
        const float* xb = x + ((size_t)b * N_PIX + q * 196) * C_DIM + c4;
        float4 acc = {0.f, 0.f, 0.f, 0.f};
#pragma unroll 7
        for (int i = 0; i < 98; ++i) {
            const int n = 2 * i + half;
            const float a = cf[n];  // wave-uniform LDS broadcast
            const float4 xv = *(const float4*)(xb + (size_t)n * C_DIM);
            acc.x += a * xv.x; acc.y += a * xv.y; acc.z += a * xv.z; acc.w += a * xv.w;
        }
        *(float4*)(part + (size_t)((j * 2) + half) * C_DIM + c4) = acc;

        // last quarter of this batch reduces the 8 partials -> out
        __threadfence();
        __syncthreads();
        if (tid == 0) {
            const int o = __hip_atomic_fetch_add(&doneP[b], 1, __ATOMIC_ACQ_REL, __HIP_MEMORY_SCOPE_AGENT);
            s_red = (o == 3);
        }
        __syncthreads();
        if (s_red) {
            __threadfence();
            const float* pp = part + (size_t)b * 8 * C_DIM;
            for (int c = tid; c < C_DIM; c += 256) {
                float s = 0.f;
#pragma unroll
                for (int jj = 0; jj < 8; ++jj) s += pp[jj * C_DIM + c];
                out[b * C_DIM + c] = s;
            }
        }
    }
}

extern "C" void kernel_launch(void* const* d_in, const int* in_sizes, int n_in,
                              void* d_out, int out_size, void* d_ws, size_t ws_size,
                              hipStream_t stream) {
    const float* x = (const float*)d_in[0];       // (128,28,28,512) fp32
    const float* anchors = (const float*)d_in[1]; // (64,512) fp32
    float* out = (float*)d_out;                   // (128,512) fp32

    ushort8* an_h = (ushort8*)d_ws;                       // 4096 frags (64 KB)
    ushort8* an_l = an_h + 4096;                          // 64 KB
    float* Tg = (float*)(an_l + 4096);                    // 128*784 fp32
    float* part = Tg + (size_t)B_DIM * N_PIX;             // 1024*512 fp32
    int* ctr = (int*)(part + (size_t)1024 * C_DIM);       // tickets + done counters (260 ints)

    anchors_norm_kernel<<<K_DIM, 64, 0, stream>>>(anchors, an_h, an_l, ctr);
    fused_kernel<<<GRID_FUSED, 256, 0, stream>>>(x, an_h, an_l, Tg, part, out, ctr);
}

// Round 3
// 422.042 us; speedup vs baseline: 1.5533x; 1.5533x over previous
//
#include <hip/hip_runtime.h>
#include <math.h>

#define C_DIM 512
#define K_DIM 64
#define N_PIX 784
#define B_DIM 128
#define NCH 16                    // 512 / 32 k-chunks
#define NT 49                     // 16-row MFMA tiles per batch (784 = 49*16)

// exp(20*d - 20) = exp2(KA*d + KB)
#define KA 28.853900817779268f
#define KB (-28.853900817779268f)

typedef __attribute__((ext_vector_type(8))) short short8;            // MFMA A/B frag (8 bf16)
typedef __attribute__((ext_vector_type(4))) float f32x4;             // MFMA C/D frag
typedef __attribute__((ext_vector_type(8))) unsigned short ushort8;  // 16B

static __device__ __forceinline__ unsigned short f2bf(float f) {
    unsigned u = __builtin_bit_cast(unsigned, f);
    u += 0x7fff + ((u >> 16) & 1);  // RNE
    return (unsigned short)(u >> 16);
}
static __device__ __forceinline__ float bf2f(unsigned short h) {
    unsigned u = ((unsigned)h) << 16;
    return __builtin_bit_cast(float, u);
}
static __device__ __forceinline__ unsigned pk_bf16(float a, float b) {
    return (unsigned)f2bf(a) | ((unsigned)f2bf(b) << 16);
}

// ---------------- Kernel A: normalize anchors -> bf16 hi/lo in MFMA-frag order --------------
// Frag for (chunk ch, col-tile ct, lane L) at index ((ch*4+ct)*64 + L), holding
// B[r = ct*16 + (L&15)][k = ch*32 + (L>>4)*8 .. +7]. (layout harness-verified in baseline)
__global__ __launch_bounds__(64) void anchors_norm_kernel(const float* __restrict__ a,
                                                          ushort8* __restrict__ an_h,
                                                          ushort8* __restrict__ an_l) {
    const int k = blockIdx.x;
    const int l = threadIdx.x;  // 0..63
    const float4* ap = (const float4*)(a + (size_t)k * C_DIM);
    float4 v0 = ap[2 * l];       // cols 8l..8l+3
    float4 v1 = ap[2 * l + 1];   // cols 8l+4..8l+7
    float ss = v0.x * v0.x + v0.y * v0.y + v0.z * v0.z + v0.w * v0.w +
               v1.x * v1.x + v1.y * v1.y + v1.z * v1.z + v1.w * v1.w;
#pragma unroll
    for (int m = 1; m < 64; m <<= 1) ss += __shfl_xor(ss, m);
    const float rn = 1.0f / (sqrtf(ss) + 1e-12f);
    const float vv[8] = {v0.x * rn, v0.y * rn, v0.z * rn, v0.w * rn,
                         v1.x * rn, v1.y * rn, v1.z * rn, v1.w * rn};
    ushort8 H, L;
#pragma unroll
    for (int i = 0; i < 8; ++i) {
        const unsigned short h = f2bf(vv[i]);
        H[i] = h;
        L[i] = f2bf(vv[i] - bf2f(h));
    }
    const int idx = (((l >> 2) * 4 + (k >> 4)) * 64) + ((k & 15) | ((l & 3) << 4));
    an_h[idx] = H;
    an_l[idx] = L;
}

// ---------------- Batch-local fused kernel ----------------
// One block per batch (128 blocks x 1024 threads = 16 waves). No cross-block
// communication of any kind (R1 post-mortem: agent-scope fences = full L2
// wb+inv, ~2800 of them killed the device; here sync = block barriers only).
//   Phase 1: anchors staged in 128 KB dynamic LDS; 49 row-tiles round-robin
//            over waves; T[784] accumulated in LDS.
//   Phase 2: block-local sinkhorn (10 iters) on LDS T.
//   Phase 3: pool re-reads x (L3-hot: touched ~40 us earlier, L2/L3 never
//            invalidated), LDS tree-reduce, direct out write.
__global__ __launch_bounds__(1024) void batch_fused(const float* __restrict__ x,
                                                    const ushort8* __restrict__ an_h,
                                                    const ushort8* __restrict__ an_l,
                                                    float* __restrict__ out) {
    extern __shared__ char dyn[];       // 131072 B: Bh[4096] ushort8, Bl[4096] ushort8
    __shared__ float T[N_PIX];          // scores, then coefficients (in-place)
    __shared__ float wsum[16];
    __shared__ float wsh;

    ushort8* Bh = (ushort8*)dyn;
    ushort8* Bl = Bh + 4096;
    float* part = (float*)dyn;          // [8][512] floats, reuses B region in phase 3

    const int b = blockIdx.x;
    const int tid = threadIdx.x;
    const int w = tid >> 6;   // wave 0..15
    const int l = tid & 63;   // lane
    const int fr = l & 15;
    const int ko = (l >> 4) * 8;  // k offset within chunk (floats)

    // stage anchor frags into LDS (2 x 64 KB), coalesced 16 B/thread
#pragma unroll
    for (int i = tid; i < 4096; i += 1024) {
        Bh[i] = an_h[i];
        Bl[i] = an_l[i];
    }
    __syncthreads();

    // ================= phase 1: cost tiles -> T in LDS =================
    for (int t = w; t < NT; t += 16) {
        const float* xr = x + (size_t)(b * N_PIX + t * 16 + fr) * C_DIM + ko;

        f32x4 acc[4];
#pragma unroll
        for (int ct = 0; ct < 4; ++ct) acc[ct] = (f32x4){0.f, 0.f, 0.f, 0.f};
        float ss = 0.f;

        // 2-deep x prefetch (64 B/lane in flight -> ~64 KB/CU, covers HBM latency
        // with only 1 block/CU resident on 128 CUs)
        float4 pa0 = *(const float4*)(xr);
        float4 pb0 = *(const float4*)(xr + 4);
        float4 pa1 = *(const float4*)(xr + 32);
        float4 pb1 = *(const float4*)(xr + 36);

#pragma unroll 1
        for (int ch = 0; ch < NCH; ++ch) {
            ushort8 A;
            *((unsigned*)&A + 0) = pk_bf16(pa0.x, pa0.y);
            *((unsigned*)&A + 1) = pk_bf16(pa0.z, pa0.w);
            *((unsigned*)&A + 2) = pk_bf16(pb0.x, pb0.y);
            *((unsigned*)&A + 3) = pk_bf16(pb0.z, pb0.w);
            ss += pa0.x * pa0.x + pa0.y * pa0.y + pa0.z * pa0.z + pa0.w * pa0.w +
                  pb0.x * pb0.x + pb0.y * pb0.y + pb0.z * pb0.z + pb0.w * pb0.w;

            // rotate + prefetch chunk ch+2
            pa0 = pa1; pb0 = pb1;
            if (ch + 2 < NCH) {
                pa1 = *(const float4*)(xr + (ch + 2) * 32);
                pb1 = *(const float4*)(xr + (ch + 2) * 32 + 4);
            }

            const short8 af = __builtin_bit_cast(short8, A);
            const int bb = ch * 256 + l;
#pragma unroll
            for (int ct = 0; ct < 4; ++ct) {
                const short8 h = __builtin_bit_cast(short8, Bh[bb + ct * 64]);
                const short8 lo = __builtin_bit_cast(short8, Bl[bb + ct * 64]);
                acc[ct] = __builtin_amdgcn_mfma_f32_16x16x32_bf16(af, h, acc[ct], 0, 0, 0);
                acc[ct] = __builtin_amdgcn_mfma_f32_16x16x32_bf16(af, lo, acc[ct], 0, 0, 0);
            }
        }

        // full-row sumsq: lanes {l, l^16, l^32, l^48} hold complementary k-slices
        ss += __shfl_xor(ss, 16);
        ss += __shfl_xor(ss, 32);
        const float rn = 1.0f / (sqrtf(ss) + 1e-12f);  // for row fr (all 4 copies agree)

        // epilogue: C/D layout col=l&15 (anchor), row=(l>>4)*4+i (x-row)
#pragma unroll
        for (int i = 0; i < 4; ++i) {
            const int r = ((l >> 4) << 2) + i;         // row within tile
            const float rnr = __shfl(rn, r);           // rn lives at lane fr==r
            float s = exp2f(KA * (acc[0][i] * rnr) + KB) +
                      exp2f(KA * (acc[1][i] * rnr) + KB) +
                      exp2f(KA * (acc[2][i] * rnr) + KB) +
                      exp2f(KA * (acc[3][i] * rnr) + KB);
            s += __shfl_xor(s, 1); s += __shfl_xor(s, 2);
            s += __shfl_xor(s, 4); s += __shfl_xor(s, 8);
            if ((l & 15) == 0) T[t * 16 + r] = s;      // lanes 0,16,32,48 -> rows r
        }
    }
    __syncthreads();

    // ================= phase 2: block-local sinkhorn =================
    const float rT = (tid < N_PIX) ? T[tid] : 0.f;
    float wv = 1.0f;
    for (int it = 0; it < 10; ++it) {
        const float wr = wv * rT;
        float p = wr / (1.0f + wr);
#pragma unroll
        for (int m = 1; m < 64; m <<= 1) p += __shfl_xor(p, m);
        if (l == 0) wsum[w] = p;
        __syncthreads();
        if (tid == 0) {
            float s2 = 0.f;
#pragma unroll
            for (int j = 0; j < 16; ++j) s2 += wsum[j];
            wsh = wv * 392.0f / s2;  // mu*N = 0.5*784
        }
        __syncthreads();
        wv = wsh;
    }
    if (tid < N_PIX) {
        const float wr = wv * rT;
        T[tid] = (2.0f / 784.0f) * wr / (1.0f + wr);  // coefficients, in place
    }
    __syncthreads();

    // ================= phase 3: pool + reduce + out =================
    // thread (r8 = tid>>7 [wave-uniform], c4 = (tid&127)*4) accumulates rows
    // n = r8 + 8*i over its float4 channel slice; x comes from L3 (never inv'd).
    const int r8 = tid >> 7;
    const int c4 = (tid & 127) * 4;
    const float* xb = x + ((size_t)b * N_PIX + r8) * C_DIM + c4;
    float4 pacc = {0.f, 0.f, 0.f, 0.f};
#pragma unroll 7
    for (int i = 0; i < 98; ++i) {
        const float a = T[r8 + 8 * i];  // wave-uniform LDS broadcast
        const float4 xv = *(const float4*)(xb + (size_t)(8 * i) * C_DIM);
        pacc.x += a * xv.x; pacc.y += a * xv.y; pacc.z += a * xv.z; pacc.w += a * xv.w;
    }
    // B region is dead past phase 1 (all waves passed the sinkhorn barriers) -> reuse
    *(float4*)(part + r8 * C_DIM + c4) = pacc;
    __syncthreads();
    if (tid < 128) {
        const int c = tid * 4;
        float4 s = {0.f, 0.f, 0.f, 0.f};
#pragma unroll
        for (int j = 0; j < 8; ++j) {
            const float4 v = *(const float4*)(part + j * C_DIM + c);
            s.x += v.x; s.y += v.y; s.z += v.z; s.w += v.w;
        }
        *(float4*)(out + (size_t)b * C_DIM + c) = s;
    }
}

extern "C" void kernel_launch(void* const* d_in, const int* in_sizes, int n_in,
                              void* d_out, int out_size, void* d_ws, size_t ws_size,
                              hipStream_t stream) {
    const float* x = (const float*)d_in[0];       // (128,28,28,512) fp32
    const float* anchors = (const float*)d_in[1]; // (64,512) fp32
    float* out = (float*)d_out;                   // (128,512) fp32

    ushort8* an_h = (ushort8*)d_ws;               // 4096 frags (64 KB)
    ushort8* an_l = an_h + 4096;                  // 64 KB

    anchors_norm_kernel<<<K_DIM, 64, 0, stream>>>(anchors, an_h, an_l);
    batch_fused<<<B_DIM, 1024, 131072, stream>>>(x, an_h, an_l, out);
}

// Round 5
// 357.720 us; speedup vs baseline: 1.8326x; 1.1798x over previous
//
#include <hip/hip_runtime.h>
#include <math.h>

#define C_DIM 512
#define K_DIM 64
#define N_PIX 784
#define B_DIM 128
#define M_ROWS (B_DIM * N_PIX)   // 100352
#define MT 128                    // rows per block tile
#define NCH 16                    // 512 / 32 chunks
#define NTILES (M_ROWS / MT)      // 784

// exp(20*d - 20) = exp2(KA*d + KB)
#define KA 28.853900817779268f
#define KB (-28.853900817779268f)

typedef __attribute__((ext_vector_type(8))) short short8;            // MFMA A/B frag (8 bf16)
typedef __attribute__((ext_vector_type(4))) float f32x4;             // MFMA C/D frag
typedef __attribute__((ext_vector_type(8))) unsigned short ushort8;  // 16B

static __device__ __forceinline__ unsigned short f2bf(float f) {
    unsigned u = __builtin_bit_cast(unsigned, f);
    u += 0x7fff + ((u >> 16) & 1);  // RNE
    return (unsigned short)(u >> 16);
}
static __device__ __forceinline__ float bf2f(unsigned short h) {
    unsigned u = ((unsigned)h) << 16;
    return __builtin_bit_cast(float, u);
}
static __device__ __forceinline__ unsigned pk_bf16(float a, float b) {
    return (unsigned)f2bf(a) | ((unsigned)f2bf(b) << 16);
}

// ---------------- Kernel A: normalize anchors -> bf16 hi/lo in MFMA-frag order --------------
// Also zeroes the fused kernel's per-batch done counters each launch.
// Frag for (chunk ch, col-tile ct, lane L) at index ((ch*4+ct)*64 + L), holding
// B[r = ct*16 + (L&15)][k = ch*32 + (L>>4)*8 .. +7]. (layout harness-verified in baseline)
__global__ __launch_bounds__(64) void anchors_norm_kernel(const float* __restrict__ a,
                                                          ushort8* __restrict__ an_h,
                                                          ushort8* __restrict__ an_l,
                                                          int* __restrict__ doneT) {
    const int k = blockIdx.x;
    const int l = threadIdx.x;  // 0..63
    if (k == 0) {
#pragma unroll
        for (int i = l; i < B_DIM; i += 64) doneT[i] = 0;
    }
    const float4* ap = (const float4*)(a + (size_t)k * C_DIM);
    float4 v0 = ap[2 * l];       // cols 8l..8l+3
    float4 v1 = ap[2 * l + 1];   // cols 8l+4..8l+7
    float ss = v0.x * v0.x + v0.y * v0.y + v0.z * v0.z + v0.w * v0.w +
               v1.x * v1.x + v1.y * v1.y + v1.z * v1.z + v1.w * v1.w;
#pragma unroll
    for (int m = 1; m < 64; m <<= 1) ss += __shfl_xor(ss, m);
    const float rn = 1.0f / (sqrtf(ss) + 1e-12f);
    const float vv[8] = {v0.x * rn, v0.y * rn, v0.z * rn, v0.w * rn,
                         v1.x * rn, v1.y * rn, v1.z * rn, v1.w * rn};
    ushort8 H, L;
#pragma unroll
    for (int i = 0; i < 8; ++i) {
        const unsigned short h = f2bf(vv[i]);
        H[i] = h;
        L[i] = f2bf(vv[i] - bf2f(h));
    }
    const int idx = (((l >> 2) * 4 + (k >> 4)) * 64) + ((k & 15) | ((l & 3) << 4));
    an_h[idx] = H;
    an_l[idx] = L;
}

// ---------------- Fused cost + last-finisher pool ----------------
// 784 blocks x 256 threads. Block t = R0's proven cost tile t (128 rows x 64
// anchors, 4 waves, B-frags from L2-hot global, no in-loop barriers). T written
// via RELAXED AGENT atomic stores (per-op write-through; NO threadfence -> no
// L2 wb+inv, the R1 killer). After __syncthreads (drains vmcnt), tid 0/1 bump
// the 7-tile done counter of the touched batch(es); whoever sees old==6 pools
// that batch inline (R0's proven sinkhorn+pool body; T read via agent atomic
// loads bypassing the possibly-stale XCD L2; x rows L3-hot). No block ever
// waits on another -> deadlock-free at any occupancy/dispatch order (G16).
__global__ __launch_bounds__(256) void cost_pool(const float* __restrict__ x,
                                                 const ushort8* __restrict__ an_h,
                                                 const ushort8* __restrict__ an_l,
                                                 float* __restrict__ Tg,
                                                 float* __restrict__ out,
                                                 int* __restrict__ doneT) {
    __shared__ float nrm[MT];
    __shared__ float cf[N_PIX];
    __shared__ float prt[2][C_DIM];
    __shared__ float wsum[4];
    __shared__ float wsh;
    __shared__ int s_pool[2];

    const int tid = threadIdx.x;
    const int m0 = blockIdx.x * MT;
    const int w = tid >> 6;   // wave 0..3
    const int l = tid & 63;   // lane
    const int fr = l & 15;
    const int ko = (l >> 4) * 8;  // k offset within chunk (floats)

    // ================= cost tile (R0 body, verbatim) =================
    const float* xr0 = x + (size_t)(m0 + w * 32 + fr) * C_DIM + ko;
    const float* xr1 = xr0 + 16 * C_DIM;

    f32x4 acc[2][4];
#pragma unroll
    for (int rt = 0; rt < 2; ++rt)
#pragma unroll
        for (int ct = 0; ct < 4; ++ct) acc[rt][ct] = (f32x4){0.f, 0.f, 0.f, 0.f};
    float ss0 = 0.f, ss1 = 0.f;

    // prefetch chunk 0
    float4 p0a = *(const float4*)(xr0);
    float4 p0b = *(const float4*)(xr0 + 4);
    float4 p1a = *(const float4*)(xr1);
    float4 p1b = *(const float4*)(xr1 + 4);
    const ushort8* bhp = an_h + l;
    const ushort8* blp = an_l + l;
    ushort8 bh[4], bl[4];
#pragma unroll
    for (int ct = 0; ct < 4; ++ct) { bh[ct] = bhp[ct * 64]; bl[ct] = blp[ct * 64]; }

#pragma unroll 1
    for (int ch = 0; ch < NCH; ++ch) {
        ushort8 A0, A1;
        *((unsigned*)&A0 + 0) = pk_bf16(p0a.x, p0a.y);
        *((unsigned*)&A0 + 1) = pk_bf16(p0a.z, p0a.w);
        *((unsigned*)&A0 + 2) = pk_bf16(p0b.x, p0b.y);
        *((unsigned*)&A0 + 3) = pk_bf16(p0b.z, p0b.w);
        *((unsigned*)&A1 + 0) = pk_bf16(p1a.x, p1a.y);
        *((unsigned*)&A1 + 1) = pk_bf16(p1a.z, p1a.w);
        *((unsigned*)&A1 + 2) = pk_bf16(p1b.x, p1b.y);
        *((unsigned*)&A1 + 3) = pk_bf16(p1b.z, p1b.w);
        ss0 += p0a.x * p0a.x + p0a.y * p0a.y + p0a.z * p0a.z + p0a.w * p0a.w +
               p0b.x * p0b.x + p0b.y * p0b.y + p0b.z * p0b.z + p0b.w * p0b.w;
        ss1 += p1a.x * p1a.x + p1a.y * p1a.y + p1a.z * p1a.z + p1a.w * p1a.w +
               p1b.x * p1b.x + p1b.y * p1b.y + p1b.z * p1b.z + p1b.w * p1b.w;
        const short8 a0 = __builtin_bit_cast(short8, A0);
        const short8 a1 = __builtin_bit_cast(short8, A1);
        ushort8 cbh[4], cbl[4];
#pragma unroll
        for (int ct = 0; ct < 4; ++ct) { cbh[ct] = bh[ct]; cbl[ct] = bl[ct]; }

        // prefetch next chunk (overlaps MFMAs)
        if (ch + 1 < NCH) {
            const int c0 = (ch + 1) * 32;
            p0a = *(const float4*)(xr0 + c0);
            p0b = *(const float4*)(xr0 + c0 + 4);
            p1a = *(const float4*)(xr1 + c0);
            p1b = *(const float4*)(xr1 + c0 + 4);
            const int bb = (ch + 1) * 4 * 64;
#pragma unroll
            for (int ct = 0; ct < 4; ++ct) {
                bh[ct] = bhp[bb + ct * 64];
                bl[ct] = blp[bb + ct * 64];
            }
        }

#pragma unroll
        for (int ct = 0; ct < 4; ++ct) {
            const short8 h = __builtin_bit_cast(short8, cbh[ct]);
            const short8 lo = __builtin_bit_cast(short8, cbl[ct]);
            acc[0][ct] = __builtin_amdgcn_mfma_f32_16x16x32_bf16(a0, h, acc[0][ct], 0, 0, 0);
            acc[0][ct] = __builtin_amdgcn_mfma_f32_16x16x32_bf16(a0, lo, acc[0][ct], 0, 0, 0);
            acc[1][ct] = __builtin_amdgcn_mfma_f32_16x16x32_bf16(a1, h, acc[1][ct], 0, 0, 0);
            acc[1][ct] = __builtin_amdgcn_mfma_f32_16x16x32_bf16(a1, lo, acc[1][ct], 0, 0, 0);
        }
    }

    // full-row sumsq: lanes {l, l+16, l+32, l+48} hold complementary k-slices
    ss0 += __shfl_xor(ss0, 16); ss0 += __shfl_xor(ss0, 32);
    ss1 += __shfl_xor(ss1, 16); ss1 += __shfl_xor(ss1, 32);
    if (l < 16) {
        nrm[w * 32 + fr] = 1.0f / (sqrtf(ss0) + 1e-12f);
        nrm[w * 32 + 16 + fr] = 1.0f / (sqrtf(ss1) + 1e-12f);
    }
    __syncthreads();

    // epilogue: C/D layout col=l&15, row=(l>>4)*4+i ; T[m] = sum_k exp(20*cos - 20)
    // T stored device-visible (relaxed agent atomic store = per-op write-through).
#pragma unroll
    for (int rt = 0; rt < 2; ++rt) {
#pragma unroll
        for (int i = 0; i < 4; ++i) {
            const int m = w * 32 + rt * 16 + ((l >> 4) << 2) + i;
            const float rn = nrm[m];
            float t = exp2f(KA * (acc[rt][0][i] * rn) + KB) +
                      exp2f(KA * (acc[rt][1][i] * rn) + KB) +
                      exp2f(KA * (acc[rt][2][i] * rn) + KB) +
                      exp2f(KA * (acc[rt][3][i] * rn) + KB);
            t += __shfl_xor(t, 1); t += __shfl_xor(t, 2);
            t += __shfl_xor(t, 4); t += __shfl_xor(t, 8);
            if ((l & 15) == 0)
                __hip_atomic_store(&Tg[m0 + m], t, __ATOMIC_RELAXED, __HIP_MEMORY_SCOPE_AGENT);
        }
    }

    // __syncthreads drains each wave's vmcnt before the barrier -> all 4 waves'
    // T-stores are at the coherent point before any done-counter bump.
    __syncthreads();
    if (tid < 2) {
        const int b0 = m0 / N_PIX;
        const int b1 = (m0 + MT - 1) / N_PIX;
        const int bb = (tid == 0) ? b0 : b1;
        const bool valid = (tid == 0) || (b1 != b0);
        int old = -1;
        if (valid)
            old = __hip_atomic_fetch_add(&doneT[bb], 1, __ATOMIC_RELAXED, __HIP_MEMORY_SCOPE_AGENT);
        s_pool[tid] = (valid && old == 6) ? bb : -1;  // 7th finisher pools batch bb
    }
    __syncthreads();

    // ================= pool (only the last finisher of a batch) =================
#pragma unroll 1
    for (int pi = 0; pi < 2; ++pi) {
        const int b = s_pool[pi];
        if (b < 0) continue;

        // sinkhorn on T[b,:] (R0 pool body; T via agent atomic loads -> bypass stale L2)
        float r[4];
#pragma unroll
        for (int qq = 0; qq < 4; ++qq) {
            const int n = tid + qq * 256;
            r[qq] = (n < N_PIX)
                        ? __hip_atomic_load(&Tg[b * N_PIX + n], __ATOMIC_RELAXED, __HIP_MEMORY_SCOPE_AGENT)
                        : 0.f;
        }
        float wv = 1.0f;
        for (int it = 0; it < 10; ++it) {
            float p = 0.f;
#pragma unroll
            for (int qq = 0; qq < 4; ++qq) {
                const float wr = wv * r[qq];
                p += wr / (1.0f + wr);
            }
#pragma unroll
            for (int m = 1; m < 64; m <<= 1) p += __shfl_xor(p, m);
            if ((tid & 63) == 0) wsum[tid >> 6] = p;
            __syncthreads();
            if (tid == 0) {
                const float s = wsum[0] + wsum[1] + wsum[2] + wsum[3];
                wsh = wv * 392.0f / s;  // mu*N = 0.5*784
            }
            __syncthreads();
            wv = wsh;
        }
#pragma unroll
        for (int qq = 0; qq < 4; ++qq) {
            const int n = tid + qq * 256;
            if (n < N_PIX) {
                const float wr = wv * r[qq];
                cf[n] = (2.0f / 784.0f) * wr / (1.0f + wr);
            }
        }
        __syncthreads();

        // pool all 784 rows: thread (r8 = tid>>7, c4=(tid&127)*4), rows 2i+r8.
        // x rows streamed by cost blocks moments ago -> L3-hot (R3 proved L3
        // serves this re-read: FETCH stayed at one pass).
        const int r8 = tid >> 7;
        const int c4 = (tid & 127) * 4;
        const float* xb = x + ((size_t)b * N_PIX + r8) * C_DIM + c4;
        float4 pacc = {0.f, 0.f, 0.f, 0.f};
#pragma unroll 7
        for (int i = 0; i < 392; ++i) {
            const float a = cf[2 * i + r8];  // wave-uniform LDS broadcast
            const float4 xv = *(const float4*)(xb + (size_t)(2 * i) * C_DIM);
            pacc.x += a * xv.x; pacc.y += a * xv.y; pacc.z += a * xv.z; pacc.w += a * xv.w;
        }
        *(float4*)(&prt[r8][c4]) = pacc;
        __syncthreads();
        if (tid < 128) {
            const int c = tid * 4;
            const float4 e = *(const float4*)(&prt[0][c]);
            const float4 o = *(const float4*)(&prt[1][c]);
            float4 s;
            s.x = e.x + o.x; s.y = e.y + o.y; s.z = e.z + o.z; s.w = e.w + o.w;
            *(float4*)(out + (size_t)b * C_DIM + c) = s;
        }
        __syncthreads();  // guard cf/prt/wsum reuse if this block pools two batches
    }
}

extern "C" void kernel_launch(void* const* d_in, const int* in_sizes, int n_in,
                              void* d_out, int out_size, void* d_ws, size_t ws_size,
                              hipStream_t stream) {
    const float* x = (const float*)d_in[0];       // (128,28,28,512) fp32
    const float* anchors = (const float*)d_in[1]; // (64,512) fp32
    float* out = (float*)d_out;                   // (128,512) fp32

    ushort8* an_h = (ushort8*)d_ws;               // 4096 frags (64 KB)
    ushort8* an_l = an_h + 4096;                  // 64 KB
    float* Tg = (float*)(an_l + 4096);            // 128*784 fp32
    int* doneT = (int*)(Tg + (size_t)B_DIM * N_PIX);  // [128] per-batch tile counters

    anchors_norm_kernel<<<K_DIM, 64, 0, stream>>>(anchors, an_h, an_l, doneT);
    cost_pool<<<NTILES, 256, 0, stream>>>(x, an_h, an_l, Tg, out, doneT);
}

// Round 6
// 330.867 us; speedup vs baseline: 1.9814x; 1.0812x over previous
//
#include <hip/hip_runtime.h>
#include <math.h>

#define C_DIM 512
#define K_DIM 64
#define N_PIX 784
#define B_DIM 128
#define M_ROWS (B_DIM * N_PIX)   // 100352
#define MT 128                    // rows per block tile
#define NCH 16                    // 512 / 32 chunks

// exp(20*d - 20) = exp2(KA*d + KB)
#define KA 28.853900817779268f
#define KB (-28.853900817779268f)

typedef __attribute__((ext_vector_type(8))) short short8;            // MFMA A/B frag (8 bf16)
typedef __attribute__((ext_vector_type(4))) float f32x4;             // MFMA C/D frag
typedef __attribute__((ext_vector_type(8))) unsigned short ushort8;  // 16B

static __device__ __forceinline__ unsigned short f2bf(float f) {
    unsigned u = __builtin_bit_cast(unsigned, f);
    u += 0x7fff + ((u >> 16) & 1);  // RNE
    return (unsigned short)(u >> 16);
}
static __device__ __forceinline__ float bf2f(unsigned short h) {
    unsigned u = ((unsigned)h) << 16;
    return __builtin_bit_cast(float, u);
}
static __device__ __forceinline__ unsigned pk_bf16(float a, float b) {
    return (unsigned)f2bf(a) | ((unsigned)f2bf(b) << 16);
}

// ---------------- Kernel A: normalize anchors -> bf16 hi/lo in MFMA-frag order --------------
// Frag for (chunk ch, col-tile ct, lane L) at index ((ch*4+ct)*64 + L), holding
// B[r = ct*16 + (L&15)][k = ch*32 + (L>>4)*8 .. +7]. (layout harness-verified, baseline)
__global__ __launch_bounds__(64) void anchors_norm_kernel(const float* __restrict__ a,
                                                          ushort8* __restrict__ an_h,
                                                          ushort8* __restrict__ an_l) {
    const int k = blockIdx.x;
    const int l = threadIdx.x;  // 0..63
    const float4* ap = (const float4*)(a + (size_t)k * C_DIM);
    float4 v0 = ap[2 * l];       // cols 8l..8l+3
    float4 v1 = ap[2 * l + 1];   // cols 8l+4..8l+7
    float ss = v0.x * v0.x + v0.y * v0.y + v0.z * v0.z + v0.w * v0.w +
               v1.x * v1.x + v1.y * v1.y + v1.z * v1.z + v1.w * v1.w;
#pragma unroll
    for (int m = 1; m < 64; m <<= 1) ss += __shfl_xor(ss, m);
    const float rn = 1.0f / (sqrtf(ss) + 1e-12f);
    const float vv[8] = {v0.x * rn, v0.y * rn, v0.z * rn, v0.w * rn,
                         v1.x * rn, v1.y * rn, v1.z * rn, v1.w * rn};
    ushort8 H, L;
#pragma unroll
    for (int i = 0; i < 8; ++i) {
        const unsigned short h = f2bf(vv[i]);
        H[i] = h;
        L[i] = f2bf(vv[i] - bf2f(h));
    }
    const int idx = (((l >> 2) * 4 + (k >> 4)) * 64) + ((k & 15) | ((l & 3) << 4));
    an_h[idx] = H;
    an_l[idx] = L;
}

// ---------------- Kernel B: cosine GEMM via MFMA + T — barrier-free (R0 verbatim) ----------
// 784 blocks x 256 threads (4 waves). Block tile 128 rows x 64 anchors; wave w owns
// rows w*32..+31. Profiled near HBM roofline (R5 occupancy decomposition).
__global__ __launch_bounds__(256) void cost_t_kernel(const float* __restrict__ x,
                                                     const ushort8* __restrict__ an_h,
                                                     const ushort8* __restrict__ an_l,
                                                     float* __restrict__ Tg) {
    __shared__ float nrm[MT];

    const int tid = threadIdx.x;
    const int m0 = blockIdx.x * MT;
    const int w = tid >> 6;   // wave 0..3
    const int l = tid & 63;   // lane
    const int fr = l & 15;
    const int ko = (l >> 4) * 8;  // k offset within chunk (floats)

    const float* xr0 = x + (size_t)(m0 + w * 32 + fr) * C_DIM + ko;
    const float* xr1 = xr0 + 16 * C_DIM;

    f32x4 acc[2][4];
#pragma unroll
    for (int rt = 0; rt < 2; ++rt)
#pragma unroll
        for (int ct = 0; ct < 4; ++ct) acc[rt][ct] = (f32x4){0.f, 0.f, 0.f, 0.f};
    float ss0 = 0.f, ss1 = 0.f;

    // prefetch chunk 0
    float4 p0a = *(const float4*)(xr0);
    float4 p0b = *(const float4*)(xr0 + 4);
    float4 p1a = *(const float4*)(xr1);
    float4 p1b = *(const float4*)(xr1 + 4);
    const ushort8* bhp = an_h + l;
    const ushort8* blp = an_l + l;
    ushort8 bh[4], bl[4];
#pragma unroll
    for (int ct = 0; ct < 4; ++ct) { bh[ct] = bhp[ct * 64]; bl[ct] = blp[ct * 64]; }

#pragma unroll 1
    for (int ch = 0; ch < NCH; ++ch) {
        ushort8 A0, A1;
        *((unsigned*)&A0 + 0) = pk_bf16(p0a.x, p0a.y);
        *((unsigned*)&A0 + 1) = pk_bf16(p0a.z, p0a.w);
        *((unsigned*)&A0 + 2) = pk_bf16(p0b.x, p0b.y);
        *((unsigned*)&A0 + 3) = pk_bf16(p0b.z, p0b.w);
        *((unsigned*)&A1 + 0) = pk_bf16(p1a.x, p1a.y);
        *((unsigned*)&A1 + 1) = pk_bf16(p1a.z, p1a.w);
        *((unsigned*)&A1 + 2) = pk_bf16(p1b.x, p1b.y);
        *((unsigned*)&A1 + 3) = pk_bf16(p1b.z, p1b.w);
        ss0 += p0a.x * p0a.x + p0a.y * p0a.y + p0a.z * p0a.z + p0a.w * p0a.w +
               p0b.x * p0b.x + p0b.y * p0b.y + p0b.z * p0b.z + p0b.w * p0b.w;
        ss1 += p1a.x * p1a.x + p1a.y * p1a.y + p1a.z * p1a.z + p1a.w * p1a.w +
               p1b.x * p1b.x + p1b.y * p1b.y + p1b.z * p1b.z + p1b.w * p1b.w;
        const short8 a0 = __builtin_bit_cast(short8, A0);
        const short8 a1 = __builtin_bit_cast(short8, A1);
        ushort8 cbh[4], cbl[4];
#pragma unroll
        for (int ct = 0; ct < 4; ++ct) { cbh[ct] = bh[ct]; cbl[ct] = bl[ct]; }

        // prefetch next chunk (overlaps MFMAs)
        if (ch + 1 < NCH) {
            const int c0 = (ch + 1) * 32;
            p0a = *(const float4*)(xr0 + c0);
            p0b = *(const float4*)(xr0 + c0 + 4);
            p1a = *(const float4*)(xr1 + c0);
            p1b = *(const float4*)(xr1 + c0 + 4);
            const int bb = (ch + 1) * 4 * 64;
#pragma unroll
            for (int ct = 0; ct < 4; ++ct) {
                bh[ct] = bhp[bb + ct * 64];
                bl[ct] = blp[bb + ct * 64];
            }
        }

#pragma unroll
        for (int ct = 0; ct < 4; ++ct) {
            const short8 h = __builtin_bit_cast(short8, cbh[ct]);
            const short8 lo = __builtin_bit_cast(short8, cbl[ct]);
            acc[0][ct] = __builtin_amdgcn_mfma_f32_16x16x32_bf16(a0, h, acc[0][ct], 0, 0, 0);
            acc[0][ct] = __builtin_amdgcn_mfma_f32_16x16x32_bf16(a0, lo, acc[0][ct], 0, 0, 0);
            acc[1][ct] = __builtin_amdgcn_mfma_f32_16x16x32_bf16(a1, h, acc[1][ct], 0, 0, 0);
            acc[1][ct] = __builtin_amdgcn_mfma_f32_16x16x32_bf16(a1, lo, acc[1][ct], 0, 0, 0);
        }
    }

    // full-row sumsq: lanes {l, l+16, l+32, l+48} hold complementary k-slices
    ss0 += __shfl_xor(ss0, 16); ss0 += __shfl_xor(ss0, 32);
    ss1 += __shfl_xor(ss1, 16); ss1 += __shfl_xor(ss1, 32);
    if (l < 16) {
        nrm[w * 32 + fr] = 1.0f / (sqrtf(ss0) + 1e-12f);
        nrm[w * 32 + 16 + fr] = 1.0f / (sqrtf(ss1) + 1e-12f);
    }
    __syncthreads();

    // epilogue: C/D layout col=l&15, row=(l>>4)*4+i ; T[m] = sum_k exp(20*cos - 20)
#pragma unroll
    for (int rt = 0; rt < 2; ++rt) {
#pragma unroll
        for (int i = 0; i < 4; ++i) {
            const int m = w * 32 + rt * 16 + ((l >> 4) << 2) + i;
            const float rn = nrm[m];
            float t = exp2f(KA * (acc[rt][0][i] * rn) + KB) +
                      exp2f(KA * (acc[rt][1][i] * rn) + KB) +
                      exp2f(KA * (acc[rt][2][i] * rn) + KB) +
                      exp2f(KA * (acc[rt][3][i] * rn) + KB);
            t += __shfl_xor(t, 1); t += __shfl_xor(t, 2);
            t += __shfl_xor(t, 4); t += __shfl_xor(t, 8);
            if ((l & 15) == 0) Tg[m0 + m] = t;
        }
    }
}

// ---------------- Kernel C: sinkhorn + weighted pooling, 8-way split ----------------
// 1024 blocks = (batch, eighth). 4 blocks/CU -> 16 waves/CU for the latency-bound
// L3 re-read (R5 post-mortem: the 2-waves/CU pool tail was the 135 us sink).
// Each block redundantly runs the scalar sinkhorn (reads T[b,:], 10 iters),
// builds coef for its 98 rows, pools them, reduces its two half-partials in LDS,
// writes ONE 512-float partial. w_{t+1} = w*(mu*N)/sum_n wT/(1+wT);
// coef = (2/N)*wT/(1+wT).
__global__ __launch_bounds__(256) void pool_partial(const float* __restrict__ x,
                                                    const float* __restrict__ Tg,
                                                    float* __restrict__ part) {
    const int bid = blockIdx.x;
    const int b = bid >> 3;
    const int o = bid & 7;
    const int tid = threadIdx.x;
    __shared__ float wsum[4];
    __shared__ float wsh;
    __shared__ float cf[98];
    __shared__ float prt[2][C_DIM];

    float r[4];
#pragma unroll
    for (int qq = 0; qq < 4; ++qq) {
        const int n = tid + qq * 256;
        r[qq] = (n < N_PIX) ? Tg[b * N_PIX + n] : 0.f;
    }
    float wv = 1.0f;
    for (int it = 0; it < 10; ++it) {
        float p = 0.f;
#pragma unroll
        for (int qq = 0; qq < 4; ++qq) {
            const float wr = wv * r[qq];
            p += wr / (1.0f + wr);
        }
#pragma unroll
        for (int m = 1; m < 64; m <<= 1) p += __shfl_xor(p, m);
        if ((tid & 63) == 0) wsum[tid >> 6] = p;
        __syncthreads();
        if (tid == 0) {
            const float s = wsum[0] + wsum[1] + wsum[2] + wsum[3];
            wsh = wv * 392.0f / s;  // mu*N = 0.5*784
        }
        __syncthreads();
        wv = wsh;
    }
    if (tid < 98) {
        const float wr = wv * Tg[b * N_PIX + o * 98 + tid];
        cf[tid] = (2.0f / 784.0f) * wr / (1.0f + wr);
    }
    __syncthreads();

    // pool this block's 98 rows: thread (half = tid>>7 [wave-uniform],
    // c4 = (tid&127)*4), rows n = 2i+half. x rows are L3-resident (205 MB < 256 MB,
    // streamed by cost_t ~40 us earlier; R3/R5 both confirmed no re-fetch).
    const int half = tid >> 7;
    const int c4 = (tid & 127) * 4;
    const float* xb = x + ((size_t)b * N_PIX + o * 98) * C_DIM + c4;
    float4 acc = {0.f, 0.f, 0.f, 0.f};
#pragma unroll 7
    for (int i = 0; i < 49; ++i) {
        const int n = 2 * i + half;
        const float a = cf[n];  // wave-uniform LDS broadcast
        const float4 xv = *(const float4*)(xb + (size_t)n * C_DIM);
        acc.x += a * xv.x; acc.y += a * xv.y; acc.z += a * xv.z; acc.w += a * xv.w;
    }
    *(float4*)(&prt[half][c4]) = acc;
    __syncthreads();
    if (tid < 128) {
        const int c = tid * 4;
        const float4 e = *(const float4*)(&prt[0][c]);
        const float4 od = *(const float4*)(&prt[1][c]);
        float4 s;
        s.x = e.x + od.x; s.y = e.y + od.y; s.z = e.z + od.z; s.w = e.w + od.w;
        *(float4*)(part + (size_t)bid * C_DIM + c) = s;
    }
}

__global__ __launch_bounds__(256) void pool_reduce(const float* __restrict__ part,
                                                   float* __restrict__ out) {
    const int i = blockIdx.x * 256 + threadIdx.x;  // over b*512 + c
    const int b = i >> 9;
    const int c = i & 511;
    const float* p = part + (size_t)b * 8 * C_DIM + c;
    float s = 0.f;
#pragma unroll
    for (int j = 0; j < 8; ++j) s += p[j * C_DIM];
    out[i] = s;
}

extern "C" void kernel_launch(void* const* d_in, const int* in_sizes, int n_in,
                              void* d_out, int out_size, void* d_ws, size_t ws_size,
                              hipStream_t stream) {
    const float* x = (const float*)d_in[0];       // (128,28,28,512) fp32
    const float* anchors = (const float*)d_in[1]; // (64,512) fp32
    float* out = (float*)d_out;                   // (128,512) fp32

    ushort8* an_h = (ushort8*)d_ws;                       // 4096 frags (64 KB)
    ushort8* an_l = an_h + 4096;                          // 64 KB
    float* Tg = (float*)(an_l + 4096);                    // 128*784 fp32
    float* part = Tg + (size_t)B_DIM * N_PIX;             // 1024*512 fp32 (2 MB)

    anchors_norm_kernel<<<K_DIM, 64, 0, stream>>>(anchors, an_h, an_l);
    cost_t_kernel<<<M_ROWS / MT, 256, 0, stream>>>(x, an_h, an_l, Tg);
    pool_partial<<<B_DIM * 8, 256, 0, stream>>>(x, Tg, part);
    pool_reduce<<<B_DIM * C_DIM / 256, 256, 0, stream>>>(part, out);
}